// Round 3
// baseline (1325.689 us; speedup 1.0000x reference)
//
#include <hip/hip_runtime.h>

#ifndef M_PI
#define M_PI 3.14159265358979323846
#endif

#define HH 512
#define WW 512
#define NBT 16
#define NH 5
#define NW 5
#define NR 3
#define NS 3
#define NCOMBO (NH * NW * NR * NS)  // 225
#define IPB 4                        // images per block
#define NG (NBT / IPB)               // 4 image groups

struct BlockParams {
  float Ax, Bx, Cx, Ay, By, Cy;
  int ch, cw, y1, x1;
};

// wave_shr:1 — lane n receives lane n+1's value; lane 63 keeps its own (bound_ctrl=false)
__device__ __forceinline__ int dpp_wshr1_i(int x) {
  return __builtin_amdgcn_update_dpp(x, x, 0x138, 0xf, 0xf, false);
}
__device__ __forceinline__ float dpp_wshr1_f(float x) {
  return __int_as_float(dpp_wshr1_i(__float_as_int(x)));
}

// interval of t such that lo <= A*t + C <= hi
__device__ __forceinline__ void interval_1d(float A, float C, float lo, float hi,
                                            float& l, float& u) {
  if (fabsf(A) > 1e-7f) {
    float a = (lo - C) / A;
    float b = (hi - C) / A;
    l = fminf(a, b);
    u = fmaxf(a, b);
  } else {
    bool in = (C >= lo && C <= hi);
    l = in ? -1e9f : 1e9f;
    u = in ? 1e9f : -1e9f;
  }
}

// One block per (combo, image-group-of-4). 512 threads; thread = one crop
// column marching down crop rows. Coordinates computed once per pixel and
// shared across the 4 images; right bilinear corners come from the
// neighboring lane via DPP wave_shr:1 with exec-masked fixup loads.
__global__ __launch_bounds__(512)
void sad_kernel(const float* __restrict__ img_all,
                const float* __restrict__ ref_all,
                const float* __restrict__ shv, const float* __restrict__ swv,
                const float* __restrict__ rvv, const float* __restrict__ scv,
                float* __restrict__ sad_out) {
  __shared__ BlockParams bp;
  __shared__ double wsum[8][IPB];
  const int combo = blockIdx.x;
  const int g = blockIdx.y;

  if (threadIdx.x == 0) {
    // ---- crop sizes (mirrors _crop_sizes; fp64 for exact int truncation) ----
    double max_ash = 0.0, max_asw = 0.0, max_r = -1e300, max_s = -1e300;
    for (int i = 0; i < NH; ++i) max_ash = fmax(max_ash, fabs((double)shv[i]));
    for (int i = 0; i < NW; ++i) max_asw = fmax(max_asw, fabs((double)swv[i]));
    for (int i = 0; i < NR; ++i) {
      float rf = rvv[i] * (float)(M_PI / 180.0);  // fp32 like reference
      max_r = fmax(max_r, (double)rf);
    }
    for (int i = 0; i < NS; ++i) max_s = fmax(max_s, (double)scv[i]);
    double t = fabs(tan(max_r));
    int ch = (int)((double)HH - (2.0 * (max_ash + 0.5 * HH * t) * max_s + 10.0));
    int cw = (int)((double)WW - (2.0 * (max_asw + 0.5 * WW * t) * max_s + 10.0));
    bp.ch = ch; bp.cw = cw;
    bp.y1 = (HH - ch) / 2; bp.x1 = (WW - cw) / 2;

    // ---- affine params: ix = Ax*wf + Bx*hf + Cx, iy = Ay*wf + By*hf + Cy ----
    int ihh = combo / (NW * NR * NS);
    int iww = (combo / (NR * NS)) % NW;
    int irr = (combo / NS) % NR;
    int iss = combo % NS;
    double s_h = (double)shv[ihh];
    double s_w = (double)swv[iww];
    float rotf = rvv[irr] * (float)(M_PI / 180.0);
    double rot = (double)rotf;
    double scl = (double)scv[iss];
    double cs = cos(rot), sn = sin(rot);
    double cWd = (WW - 1) * 0.5, cHd = (HH - 1) * 0.5;
    double kx = ((double)WW / (WW - 1)) / scl;
    double ky = ((double)HH / (HH - 1)) / scl;
    bp.Ax = (float)(cs * kx);
    bp.Bx = (float)(sn * kx);
    bp.Cx = (float)(kx * (cs * (s_w - cWd) + sn * (s_h - cHd)) + cWd);
    bp.Ay = (float)(-sn * ky);
    bp.By = (float)(cs * ky);
    bp.Cy = (float)(ky * (-sn * (s_w - cWd) + cs * (s_h - cHd)) + cHd);
  }
  __syncthreads();

  const int ch = bp.ch, cw = bp.cw, y1 = bp.y1, x1 = bp.x1;
  const float Ax = bp.Ax, Bx = bp.Bx, Cx = bp.Cx;
  const float Ay = bp.Ay, By = bp.By, Cy = bp.Cy;
  const float* img[IPB];
  const float* ref[IPB];
#pragma unroll
  for (int j = 0; j < IPB; ++j) {
    img[j] = img_all + (size_t)(g * IPB + j) * (HH * WW);
    ref[j] = ref_all + (size_t)(g * IPB + j) * (HH * WW);
  }
  const int tid = threadIdx.x;

  const int wEff = (tid < cw) ? tid : (cw - 1);
  const float wf = (float)(x1 + wEff);
  const float colx = fmaf(Ax, wf, Cx);
  const float coly = fmaf(Ay, wf, Cy);

  // fast-valid h interval: ix,iy in [0.01, 510.98] -> all masks 1, clamps no-op
  float lx, ux, ly, uy;
  interval_1d(Bx, colx, 0.01f, 510.98f, lx, ux);
  interval_1d(By, coly, 0.01f, 510.98f, ly, uy);
  float hl = fmaxf(lx, ly);
  float hu = fminf(ux, uy);
  hl = fmaxf(fminf(hl, 2000.0f), -2000.0f);
  hu = fmaxf(fminf(hu, 2000.0f), -2000.0f);
  int lo = (int)ceilf(hl) - y1;
  int hi = (int)floorf(hu) - y1 + 1;
  lo = min(max(lo, 0), ch);
  hi = min(max(hi, lo), ch);
  for (int off = 32; off; off >>= 1) {
    lo = max(lo, __shfl_xor(lo, off));
    hi = min(hi, __shfl_xor(hi, off));
  }
  hi = max(hi, lo);
  lo = __builtin_amdgcn_readfirstlane(lo);
  hi = __builtin_amdgcn_readfirstlane(hi);

  float acc[IPB] = {0.f, 0.f, 0.f, 0.f};
  float hf = (float)y1;
  uint32_t refoff = (uint32_t)(y1 * WW + x1 + wEff);

#define SLOW_PX do { \
    float ix = fmaf(Bx, hf, colx); \
    float iy = fmaf(By, hf, coly); \
    float x0f = floorf(ix), y0f = floorf(iy); \
    float x1f = x0f + 1.0f, y1f = y0f + 1.0f; \
    float wx1 = ix - x0f, wy1 = iy - y0f; \
    float wx0 = 1.0f - wx1, wy0 = 1.0f - wy1; \
    float wx0m = (x0f >= 0.0f && x0f <= 511.0f) ? wx0 : 0.0f; \
    float wx1m = (x1f >= 0.0f && x1f <= 511.0f) ? wx1 : 0.0f; \
    float wy0m = (y0f >= 0.0f && y0f <= 511.0f) ? wy0 : 0.0f; \
    float wy1m = (y1f >= 0.0f && y1f <= 511.0f) ? wy1 : 0.0f; \
    int xc0 = (int)fminf(fmaxf(x0f, 0.0f), 511.0f); \
    int xc1 = (int)fminf(fmaxf(x1f, 0.0f), 511.0f); \
    int yc0 = (int)fminf(fmaxf(y0f, 0.0f), 511.0f); \
    int yc1 = (int)fminf(fmaxf(y1f, 0.0f), 511.0f); \
    uint32_t o00 = (uint32_t)((yc0 << 9) + xc0); \
    uint32_t o01 = (uint32_t)((yc0 << 9) + xc1); \
    uint32_t o10 = (uint32_t)((yc1 << 9) + xc0); \
    uint32_t o11 = (uint32_t)((yc1 << 9) + xc1); \
    _Pragma("unroll") \
    for (int j = 0; j < IPB; ++j) { \
      float top = img[j][o00] * wx0m + img[j][o01] * wx1m; \
      float bot = img[j][o10] * wx0m + img[j][o11] * wx1m; \
      float val = top * wy0m + bot * wy1m; \
      acc[j] += fabsf(val - ref[j][refoff]); \
    } \
    hf += 1.0f; refoff += WW; \
  } while (0)

  for (int h = 0; h < lo; ++h) SLOW_PX;

  for (int h = lo; h < hi; ++h) {
    float ix = fmaf(Bx, hf, colx);
    float iy = fmaf(By, hf, coly);
    float x0f = floorf(ix), y0f = floorf(iy);
    float wx1 = ix - x0f, wy1 = iy - y0f;
    int xi = (int)x0f, yi = (int)y0f;
    int off = (yi << 9) + xi;
    int offU = dpp_wshr1_i(off);
    bool bad = (offU != off + 1);  // x-gap, y-step, or lane 63 -> fixup load
    uint32_t uoff = (uint32_t)off;

    float v00[IPB], v10[IPB], rr[IPB], v01[IPB], v11[IPB];
#pragma unroll
    for (int j = 0; j < IPB; ++j) {
      v00[j] = img[j][uoff];
      v10[j] = img[j][uoff + 512u];
      rr[j] = ref[j][refoff];
    }
#pragma unroll
    for (int j = 0; j < IPB; ++j) {
      v01[j] = dpp_wshr1_f(v00[j]);
      v11[j] = dpp_wshr1_f(v10[j]);
    }
    if (bad) {
#pragma unroll
      for (int j = 0; j < IPB; ++j) {
        v01[j] = img[j][uoff + 1u];
        v11[j] = img[j][uoff + 513u];
      }
    }
#pragma unroll
    for (int j = 0; j < IPB; ++j) {
      float top = fmaf(wx1, v01[j] - v00[j], v00[j]);
      float bot = fmaf(wx1, v11[j] - v10[j], v10[j]);
      float val = fmaf(wy1, bot - top, top);
      acc[j] += fabsf(val - rr[j]);
    }
    hf += 1.0f; refoff += WW;
  }

  for (int h = hi; h < ch; ++h) SLOW_PX;
#undef SLOW_PX

  if (tid >= cw) {
#pragma unroll
    for (int j = 0; j < IPB; ++j) acc[j] = 0.0f;
  }

  // reduce: per-thread fp32 column partial -> fp64 wave shuffle -> LDS
  const int lane = tid & 63, wv = tid >> 6;
#pragma unroll
  for (int j = 0; j < IPB; ++j) {
    double d = (double)acc[j];
    for (int off2 = 32; off2; off2 >>= 1) d += __shfl_down(d, off2);
    if (lane == 0) wsum[wv][j] = d;
  }
  __syncthreads();
  if (tid < IPB) {
    double tot = 0.0;
    for (int i = 0; i < 8; ++i) tot += wsum[i][tid];
    sad_out[combo * NBT + g * IPB + tid] = (float)(tot / (double)(ch * cw));
  }
}

// argmin over 225 combos per image + subpixel refinement (fp32, mirrors ref)
__global__ void argmin_kernel(const float* __restrict__ sad,
                              const float* __restrict__ shv,
                              const float* __restrict__ swv,
                              const float* __restrict__ rvv,
                              const float* __restrict__ scv,
                              float* __restrict__ out) {
  const int bt = threadIdx.x;
  if (bt >= NBT) return;
  float best = sad[bt];
  int bi = 0;
  for (int c = 1; c < NCOMBO; ++c) {
    float v = sad[c * NBT + bt];
    if (v < best) { best = v; bi = c; }  // strict < keeps first occurrence
  }
  int ihh = bi / (NW * NR * NS);
  int iww = (bi / (NR * NS)) % NW;
  int irr = (bi / NS) % NR;
  int iss = bi % NS;
  ihh = min(max(ihh, 1), NH - 2);
  iww = min(max(iww, 1), NW - 2);
  irr = min(max(irr, 1), NR - 2);
  iss = min(max(iss, 1), NS - 2);
  const int c0 = ihh * (NW * NR * NS) + iww * (NR * NS) + irr * NS + iss;
  const float y2 = sad[c0 * NBT + bt];

  const int strides[4] = { NW * NR * NS, NR * NS, NS, 1 };
  const float* vecs[4] = { shv, swv, rvv, scv };
  const int idxs[4] = { ihh, iww, irr, iss };
  for (int d = 0; d < 4; ++d) {
    float ya = sad[(c0 - strides[d]) * NBT + bt];
    float yc = sad[(c0 + strides[d]) * NBT + bt];
    float denom = ya - 2.0f * y2 + yc;
    denom = (fabsf(denom) < 1e-12f) ? 1e-12f : denom;
    float delta = 0.5f * (ya - yc) / denom;
    delta = fminf(fmaxf(delta, -1.0f), 1.0f);
    float step = vecs[d][1] - vecs[d][0];
    out[d * NBT + bt] = vecs[d][idxs[d]] + delta * step;
  }
}

extern "C" void kernel_launch(void* const* d_in, const int* in_sizes, int n_in,
                              void* d_out, int out_size, void* d_ws, size_t ws_size,
                              hipStream_t stream) {
  const float* matrix = (const float*)d_in[0];
  const float* refm   = (const float*)d_in[1];
  const float* shv    = (const float*)d_in[2];
  const float* swv    = (const float*)d_in[3];
  const float* rvv    = (const float*)d_in[4];
  const float* scv    = (const float*)d_in[5];
  float* out = (float*)d_out;
  float* sad = out + 4 * NBT;  // SAD chunk lives at offset 64 in d_out

  dim3 grid(NCOMBO, NG);
  sad_kernel<<<grid, 512, 0, stream>>>(matrix, refm, shv, swv, rvv, scv, sad);
  argmin_kernel<<<1, 64, 0, stream>>>(sad, shv, swv, rvv, scv, out);
}

// Round 4
// 827.296 us; speedup vs baseline: 1.6024x; 1.6024x over previous
//
#include <hip/hip_runtime.h>

#ifndef M_PI
#define M_PI 3.14159265358979323846
#endif

#define HH 512
#define WW 512
#define NBT 16
#define NH 5
#define NW 5
#define NR 3
#define NS 3
#define NCOMBO (NH * NW * NR * NS)  // 225

struct BlockParams {
  float Ax, Bx, Cx, Ay, By, Cy;
  int ch, cw, y1, x1;
};

// wave_shl:1 (0x130) — lane n sources lane n+1; lane 63 keeps old (bound_ctrl=false).
// Self-protecting: consumers verify via offU == off+4 and fall back to loads.
__device__ __forceinline__ int dpp_nextlane_i(int x) {
  return __builtin_amdgcn_update_dpp(x, x, 0x130, 0xf, 0xf, false);
}
__device__ __forceinline__ float dpp_nextlane_f(float x) {
  return __int_as_float(dpp_nextlane_i(__float_as_int(x)));
}

// load float at byte offset from uniform base -> global_load saddr + voffset
__device__ __forceinline__ float ldg_off(const float* base, uint32_t byteOff) {
  return *reinterpret_cast<const float*>(reinterpret_cast<const char*>(base) + byteOff);
}

// interval of t such that lo <= A*t + C <= hi
__device__ __forceinline__ void interval_1d(float A, float C, float lo, float hi,
                                            float& l, float& u) {
  if (fabsf(A) > 1e-7f) {
    float a = (lo - C) / A;
    float b = (hi - C) / A;
    l = fminf(a, b);
    u = fmaxf(a, b);
  } else {
    bool in = (C >= lo && C <= hi);
    l = in ? -1e9f : 1e9f;
    u = in ? 1e9f : -1e9f;
  }
}

// One block per (combo, image). 512 threads; thread = one crop column,
// marching down crop rows. Fast/slow h-split is analytic and wave-uniform.
// Fast path: 3 loads/px (v00, v10, ref), right corners via DPP wave_shl:1
// with exec-masked fixups; 2-row unroll for MLP.
__global__ __launch_bounds__(512)
void sad_kernel(const float* __restrict__ img_all,
                const float* __restrict__ ref_all,
                const float* __restrict__ shv, const float* __restrict__ swv,
                const float* __restrict__ rvv, const float* __restrict__ scv,
                float* __restrict__ sad_out) {
  __shared__ BlockParams bp;
  __shared__ double wsum[8];
  const int combo = blockIdx.x;
  const int bt = blockIdx.y;

  if (threadIdx.x == 0) {
    // ---- crop sizes (mirrors _crop_sizes; fp64 for exact int truncation) ----
    double max_ash = 0.0, max_asw = 0.0, max_r = -1e300, max_s = -1e300;
    for (int i = 0; i < NH; ++i) max_ash = fmax(max_ash, fabs((double)shv[i]));
    for (int i = 0; i < NW; ++i) max_asw = fmax(max_asw, fabs((double)swv[i]));
    for (int i = 0; i < NR; ++i) {
      float rf = rvv[i] * (float)(M_PI / 180.0);  // fp32 like reference
      max_r = fmax(max_r, (double)rf);
    }
    for (int i = 0; i < NS; ++i) max_s = fmax(max_s, (double)scv[i]);
    double t = fabs(tan(max_r));
    int ch = (int)((double)HH - (2.0 * (max_ash + 0.5 * HH * t) * max_s + 10.0));
    int cw = (int)((double)WW - (2.0 * (max_asw + 0.5 * WW * t) * max_s + 10.0));
    bp.ch = ch; bp.cw = cw;
    bp.y1 = (HH - ch) / 2; bp.x1 = (WW - cw) / 2;

    // ---- affine: ix = Ax*wf + Bx*hf + Cx, iy = Ay*wf + By*hf + Cy ----
    int ihh = combo / (NW * NR * NS);
    int iww = (combo / (NR * NS)) % NW;
    int irr = (combo / NS) % NR;
    int iss = combo % NS;
    double s_h = (double)shv[ihh];
    double s_w = (double)swv[iww];
    float rotf = rvv[irr] * (float)(M_PI / 180.0);
    double rot = (double)rotf;
    double scl = (double)scv[iss];
    double cs = cos(rot), sn = sin(rot);
    double cWd = (WW - 1) * 0.5, cHd = (HH - 1) * 0.5;
    double kx = ((double)WW / (WW - 1)) / scl;
    double ky = ((double)HH / (HH - 1)) / scl;
    bp.Ax = (float)(cs * kx);
    bp.Bx = (float)(sn * kx);
    bp.Cx = (float)(kx * (cs * (s_w - cWd) + sn * (s_h - cHd)) + cWd);
    bp.Ay = (float)(-sn * ky);
    bp.By = (float)(cs * ky);
    bp.Cy = (float)(ky * (-sn * (s_w - cWd) + cs * (s_h - cHd)) + cHd);
  }
  __syncthreads();

  const int ch = bp.ch, cw = bp.cw, y1 = bp.y1, x1 = bp.x1;
  const float Ax = bp.Ax, Bx = bp.Bx, Cx = bp.Cx;
  const float Ay = bp.Ay, By = bp.By, Cy = bp.Cy;
  const float* __restrict__ img = img_all + (size_t)bt * (HH * WW);
  const float* __restrict__ ref = ref_all + (size_t)bt * (HH * WW);
  const int tid = threadIdx.x;

  const int wEff = (tid < cw) ? tid : (cw - 1);
  const float wf = (float)(x1 + wEff);
  const float colx = fmaf(Ax, wf, Cx);
  const float coly = fmaf(Ay, wf, Cy);

  // fast-valid h interval: ix,iy in [0.01, 510.98] -> no masks, no clamps
  float lx, ux, ly, uy;
  interval_1d(Bx, colx, 0.01f, 510.98f, lx, ux);
  interval_1d(By, coly, 0.01f, 510.98f, ly, uy);
  float hl = fmaxf(lx, ly);
  float hu = fminf(ux, uy);
  hl = fmaxf(fminf(hl, 2000.0f), -2000.0f);
  hu = fmaxf(fminf(hu, 2000.0f), -2000.0f);
  int lo = (int)ceilf(hl) - y1;
  int hi = (int)floorf(hu) - y1 + 1;
  lo = min(max(lo, 0), ch);
  hi = min(max(hi, lo), ch);
  for (int off = 32; off; off >>= 1) {
    lo = max(lo, __shfl_xor(lo, off));
    hi = min(hi, __shfl_xor(hi, off));
  }
  hi = max(hi, lo);
  lo = __builtin_amdgcn_readfirstlane(lo);
  hi = __builtin_amdgcn_readfirstlane(hi);

  float acc0 = 0.0f, acc1 = 0.0f;
  float hf = (float)y1;
  uint32_t refoffB = (uint32_t)(y1 * WW + x1 + wEff) << 2;  // byte offset

#define SLOW_PX do { \
    float ix = fmaf(Bx, hf, colx); \
    float iy = fmaf(By, hf, coly); \
    float x0f = floorf(ix), y0f = floorf(iy); \
    float x1f = x0f + 1.0f, y1f = y0f + 1.0f; \
    float wx1 = ix - x0f, wy1 = iy - y0f; \
    float wx0 = 1.0f - wx1, wy0 = 1.0f - wy1; \
    float wx0m = (x0f >= 0.0f && x0f <= 511.0f) ? wx0 : 0.0f; \
    float wx1m = (x1f >= 0.0f && x1f <= 511.0f) ? wx1 : 0.0f; \
    float wy0m = (y0f >= 0.0f && y0f <= 511.0f) ? wy0 : 0.0f; \
    float wy1m = (y1f >= 0.0f && y1f <= 511.0f) ? wy1 : 0.0f; \
    uint32_t xc0 = (uint32_t)(int)fminf(fmaxf(x0f, 0.0f), 511.0f); \
    uint32_t xc1 = (uint32_t)(int)fminf(fmaxf(x1f, 0.0f), 511.0f); \
    uint32_t yc0 = (uint32_t)(int)fminf(fmaxf(y0f, 0.0f), 511.0f); \
    uint32_t yc1 = (uint32_t)(int)fminf(fmaxf(y1f, 0.0f), 511.0f); \
    uint32_t r0b = (yc0 << 11), r1b = (yc1 << 11); \
    float top = ldg_off(img, r0b + (xc0 << 2)) * wx0m + ldg_off(img, r0b + (xc1 << 2)) * wx1m; \
    float bot = ldg_off(img, r1b + (xc0 << 2)) * wx0m + ldg_off(img, r1b + (xc1 << 2)) * wx1m; \
    float val = top * wy0m + bot * wy1m; \
    acc0 += fabsf(val - ldg_off(ref, refoffB)); \
    hf += 1.0f; refoffB += 2048u; \
  } while (0)

  for (int h = 0; h < lo; ++h) SLOW_PX;

  // ---- fast interior: 2-row unroll, independent chains ----
  int h = lo;
  for (; h + 2 <= hi; h += 2) {
    float ixa = fmaf(Bx, hf, colx), iya = fmaf(By, hf, coly);
    float hfb = hf + 1.0f;
    float ixb = fmaf(Bx, hfb, colx), iyb = fmaf(By, hfb, coly);
    float x0a = floorf(ixa), y0a = floorf(iya);
    float x0b = floorf(ixb), y0b = floorf(iyb);
    float wxa = ixa - x0a, wya = iya - y0a;
    float wxb = ixb - x0b, wyb = iyb - y0b;
    uint32_t offa = ((uint32_t)(int)y0a << 11) + ((uint32_t)(int)x0a << 2);
    uint32_t offb = ((uint32_t)(int)y0b << 11) + ((uint32_t)(int)x0b << 2);

    float v00a = ldg_off(img, offa), v10a = ldg_off(img, offa + 2048u);
    float v00b = ldg_off(img, offb), v10b = ldg_off(img, offb + 2048u);
    float rra = ldg_off(ref, refoffB), rrb = ldg_off(ref, refoffB + 2048u);

    int offUa = dpp_nextlane_i((int)offa);
    int offUb = dpp_nextlane_i((int)offb);
    float v01a = dpp_nextlane_f(v00a), v11a = dpp_nextlane_f(v10a);
    float v01b = dpp_nextlane_f(v00b), v11b = dpp_nextlane_f(v10b);
    bool bada = (offUa != (int)offa + 4);
    bool badb = (offUb != (int)offb + 4);
    if (bada) { v01a = ldg_off(img, offa + 4u); v11a = ldg_off(img, offa + 2052u); }
    if (badb) { v01b = ldg_off(img, offb + 4u); v11b = ldg_off(img, offb + 2052u); }

    float topa = fmaf(wxa, v01a - v00a, v00a);
    float bota = fmaf(wxa, v11a - v10a, v10a);
    float vala = fmaf(wya, bota - topa, topa);
    acc0 += fabsf(vala - rra);
    float topb = fmaf(wxb, v01b - v00b, v00b);
    float botb = fmaf(wxb, v11b - v10b, v10b);
    float valb = fmaf(wyb, botb - topb, topb);
    acc1 += fabsf(valb - rrb);

    hf = hfb + 1.0f;
    refoffB += 4096u;
  }
  for (; h < hi; ++h) {
    float ix = fmaf(Bx, hf, colx), iy = fmaf(By, hf, coly);
    float x0f = floorf(ix), y0f = floorf(iy);
    float wx1 = ix - x0f, wy1 = iy - y0f;
    uint32_t off = ((uint32_t)(int)y0f << 11) + ((uint32_t)(int)x0f << 2);
    float v00 = ldg_off(img, off), v10 = ldg_off(img, off + 2048u);
    float rr = ldg_off(ref, refoffB);
    int offU = dpp_nextlane_i((int)off);
    float v01 = dpp_nextlane_f(v00), v11 = dpp_nextlane_f(v10);
    if (offU != (int)off + 4) {
      v01 = ldg_off(img, off + 4u); v11 = ldg_off(img, off + 2052u);
    }
    float top = fmaf(wx1, v01 - v00, v00);
    float bot = fmaf(wx1, v11 - v10, v10);
    float val = fmaf(wy1, bot - top, top);
    acc0 += fabsf(val - rr);
    hf += 1.0f; refoffB += 2048u;
  }

  for (int h2 = hi; h2 < ch; ++h2) SLOW_PX;
#undef SLOW_PX

  float acc = acc0 + acc1;
  if (tid >= cw) acc = 0.0f;

  // reduce: fp32 per-thread partials -> fp64 wave shuffle -> LDS -> thread 0
  double d = (double)acc;
  for (int off = 32; off; off >>= 1) d += __shfl_down(d, off);
  const int lane = tid & 63, wv = tid >> 6;
  if (lane == 0) wsum[wv] = d;
  __syncthreads();
  if (tid == 0) {
    double tot = 0.0;
    for (int i = 0; i < 8; ++i) tot += wsum[i];
    sad_out[combo * NBT + bt] = (float)(tot / (double)(ch * cw));
  }
}

// argmin over 225 combos per image + subpixel refinement (fp32, mirrors ref)
__global__ void argmin_kernel(const float* __restrict__ sad,
                              const float* __restrict__ shv,
                              const float* __restrict__ swv,
                              const float* __restrict__ rvv,
                              const float* __restrict__ scv,
                              float* __restrict__ out) {
  const int bt = threadIdx.x;
  if (bt >= NBT) return;
  float best = sad[bt];
  int bi = 0;
  for (int c = 1; c < NCOMBO; ++c) {
    float v = sad[c * NBT + bt];
    if (v < best) { best = v; bi = c; }  // strict < keeps first occurrence
  }
  int ihh = bi / (NW * NR * NS);
  int iww = (bi / (NR * NS)) % NW;
  int irr = (bi / NS) % NR;
  int iss = bi % NS;
  ihh = min(max(ihh, 1), NH - 2);
  iww = min(max(iww, 1), NW - 2);
  irr = min(max(irr, 1), NR - 2);
  iss = min(max(iss, 1), NS - 2);
  const int c0 = ihh * (NW * NR * NS) + iww * (NR * NS) + irr * NS + iss;
  const float y2 = sad[c0 * NBT + bt];

  const int strides[4] = { NW * NR * NS, NR * NS, NS, 1 };
  const float* vecs[4] = { shv, swv, rvv, scv };
  const int idxs[4] = { ihh, iww, irr, iss };
  for (int d = 0; d < 4; ++d) {
    float ya = sad[(c0 - strides[d]) * NBT + bt];
    float yc = sad[(c0 + strides[d]) * NBT + bt];
    float denom = ya - 2.0f * y2 + yc;
    denom = (fabsf(denom) < 1e-12f) ? 1e-12f : denom;
    float delta = 0.5f * (ya - yc) / denom;
    delta = fminf(fmaxf(delta, -1.0f), 1.0f);
    float step = vecs[d][1] - vecs[d][0];
    out[d * NBT + bt] = vecs[d][idxs[d]] + delta * step;
  }
}

extern "C" void kernel_launch(void* const* d_in, const int* in_sizes, int n_in,
                              void* d_out, int out_size, void* d_ws, size_t ws_size,
                              hipStream_t stream) {
  const float* matrix = (const float*)d_in[0];
  const float* refm   = (const float*)d_in[1];
  const float* shv    = (const float*)d_in[2];
  const float* swv    = (const float*)d_in[3];
  const float* rvv    = (const float*)d_in[4];
  const float* scv    = (const float*)d_in[5];
  float* out = (float*)d_out;
  float* sad = out + 4 * NBT;  // SAD chunk lives at offset 64 in d_out

  dim3 grid(NCOMBO, NBT);
  sad_kernel<<<grid, 512, 0, stream>>>(matrix, refm, shv, swv, rvv, scv, sad);
  argmin_kernel<<<1, 64, 0, stream>>>(sad, shv, swv, rvv, scv, out);
}